// Round 5
// baseline (287.060 us; speedup 1.0000x reference)
//
#include <hip/hip_runtime.h>

// N=8192 nodes, D=512, E=262144. NEG=-1e6 => exp underflows to exactly 0,
// so softmax is EXACTLY sparse over each row's neighbor set (bitmask dedupes
// duplicate edges, matching .at[].set(1.0) idempotence).
//
// R5: attn = wave-per-row + work-stealing (tail balance) + 4-wide MLP.
//     gemm = XOR-swizzled LDS frag layout (4-way instead of 8-way bank
//     conflicts) + transposed vectorized epilogue (dwordx4 stores).

#define N_NODES 8192
#define DIM 512
#define MASK_WORDS 256   // 8192 bits / 32
#define CAPW 512         // per-wave neighbor chunk capacity

typedef __attribute__((ext_vector_type(8))) short short8;
typedef __attribute__((ext_vector_type(4))) float f32x4;

__device__ __forceinline__ unsigned short f2bf(float f) {
    unsigned int u = __float_as_uint(f);
    u += 0x7fffu + ((u >> 16) & 1u);          // round-to-nearest-even
    return (unsigned short)(u >> 16);
}
__device__ __forceinline__ float bf_lo(unsigned int w) { return __uint_as_float(w << 16); }
__device__ __forceinline__ float bf_hi(unsigned int w) { return __uint_as_float(w & 0xffff0000u); }

__device__ __forceinline__ float wred_sum(float s) {
    #pragma unroll
    for (int off = 1; off <= 32; off <<= 1) s += __shfl_xor(s, off, 64);
    return s;
}
__device__ __forceinline__ float wred_max(float s) {
    #pragma unroll
    for (int off = 1; off <= 32; off <<= 1) s = fmaxf(s, __shfl_xor(s, off, 64));
    return s;
}
__device__ __forceinline__ int wred_sumi(int s) {
    #pragma unroll
    for (int off = 1; off <= 32; off <<= 1) s += __shfl_xor(s, off, 64);
    return s;
}
__device__ __forceinline__ float dot8(uint4 a, uint4 b) {
    return bf_lo(a.x) * bf_lo(b.x) + bf_hi(a.x) * bf_hi(b.x)
         + bf_lo(a.y) * bf_lo(b.y) + bf_hi(a.y) * bf_hi(b.y)
         + bf_lo(a.z) * bf_lo(b.z) + bf_hi(a.z) * bf_hi(b.z)
         + bf_lo(a.w) * bf_lo(b.w) + bf_hi(a.w) * bf_hi(b.w);
}

// ---------------------------------------------------------------------------
// prep1: [0,4096) convert x -> bf16 AND zero 2KB of mask each (+ ctr) |
//        [4096,4864) transpose-convert W -> Wt
// ---------------------------------------------------------------------------
__global__ __launch_bounds__(256) void prep1(
    const float* __restrict__ x, unsigned short* __restrict__ xb,
    const float* __restrict__ Wq, const float* __restrict__ Wk,
    const float* __restrict__ Wv, unsigned short* __restrict__ Wt,
    unsigned int* __restrict__ mask, int* __restrict__ ctr)
{
    __shared__ float sm[32][33];
    const int b = blockIdx.x;
    if (b < 4096) {
        if (b == 0 && threadIdx.x == 0) *ctr = 0;   // work-steal counter
        int i = b * 256 + threadIdx.x;
        float4 f = ((const float4*)x)[i];
        ushort4 o;
        o.x = f2bf(f.x); o.y = f2bf(f.y); o.z = f2bf(f.z); o.w = f2bf(f.w);
        ((ushort4*)xb)[i] = o;
        ((uint2*)mask)[i] = make_uint2(0u, 0u);     // 4096*256*8B = 8MB
    } else {
        int bb = b - 4096;
        int which = bb >> 8, t = bb & 255;
        const float* __restrict__ W = (which == 0) ? Wq : (which == 1) ? Wk : Wv;
        unsigned short* __restrict__ outp = Wt + (size_t)which * DIM * DIM;
        int n0 = (t & 15) * 32, k0 = (t >> 4) * 32;
        int tx = threadIdx.x & 31, ty = threadIdx.x >> 5;
        #pragma unroll
        for (int r = 0; r < 4; ++r)
            sm[ty + 8 * r][tx] = W[(size_t)(k0 + ty + 8 * r) * DIM + n0 + tx];
        __syncthreads();
        #pragma unroll
        for (int r = 0; r < 4; ++r)
            outp[(size_t)(n0 + ty + 8 * r) * DIM + k0 + tx] = f2bf(sm[tx][ty + 8 * r]);
    }
}

// prep2: edge scatter (needs fully-zeroed mask)
__global__ __launch_bounds__(256) void prep2(
    const int* __restrict__ ei, unsigned int* __restrict__ mask, int E)
{
    int e = blockIdx.x * 256 + threadIdx.x;
    if (e >= E) return;
    int src = ei[e];
    int dst = ei[E + e];
    atomicOr(&mask[(size_t)src * MASK_WORDS + (dst >> 5)], 1u << (dst & 31));
}

// ---------------------------------------------------------------------------
// bf16 MFMA GEMM, 128x128 tile, BK=32, global_load_lds staging.
// XCD swizzle: p%8 = XCD owns M-tiles [xcd*8, xcd*8+8) x 12 N-tiles (q/k/v).
// LDS chunk (m, c) holds global k-group (c ^ (m&3)) -> frag reads are 4-way
// instead of 8-way bank-conflicted. Transposed epilogue via LDS: dwordx4
// stores instead of 64 ushort scatters.
// ---------------------------------------------------------------------------
__device__ __forceinline__ void load_lds16(const unsigned short* g, unsigned short* l) {
    __builtin_amdgcn_global_load_lds(
        (const __attribute__((address_space(1))) unsigned int*)g,
        (__attribute__((address_space(3))) unsigned int*)l, 16, 0, 0);
}

__global__ __launch_bounds__(256) void mfma_gemm(
    const unsigned short* __restrict__ xb, const unsigned short* __restrict__ Wt,
    const float* __restrict__ bq, const float* __restrict__ bk, const float* __restrict__ bv,
    unsigned short* __restrict__ qkv)
{
    const int p = blockIdx.x;
    const int xcd = p & 7;
    const int s = p >> 3;             // 0..95
    const int mloc = s / 12;          // 0..7
    const int n = s - 12 * mloc;      // 0..11
    const int which = n >> 2;
    const int row0 = (xcd * 8 + mloc) << 7;
    const int col0 = (n & 3) << 7;

    const unsigned short* __restrict__ Bm = Wt + (size_t)which * DIM * DIM;
    const float* __restrict__ bias = (which == 0) ? bq : (which == 1) ? bk : bv;
    unsigned short* __restrict__ outp = qkv + (size_t)which * N_NODES * DIM;

    const int tid = threadIdx.x;
    const int lane = tid & 63;
    const int w = tid >> 6;
    const int wm = (w >> 1) * 64;
    const int wn = (w & 1) * 64;
    const int L = lane & 15;
    const int quad = lane >> 4;

    __shared__ unsigned short smem[8192];     // As=smem[0:4096], Bs=smem[4096:8192]
    unsigned short* As = smem;
    unsigned short* Bs = smem + 4096;

    f32x4 zero = {0.f, 0.f, 0.f, 0.f};
    f32x4 acc[4][4];
    #pragma unroll
    for (int i = 0; i < 4; ++i)
        #pragma unroll
        for (int j = 0; j < 4; ++j) acc[i][j] = zero;

    // staging: chunk ch = (m, c), m=ch>>2, c=ch&3; holds global k-group
    // (c ^ (m&3)), i.e. global ko = (c ^ (m&3))*8.
    const int m0 = tid >> 2;
    const int cg = tid & 3;
    const int ko0 = (cg ^ (m0 & 3)) << 3;
    const int ko1 = (cg ^ ((m0 + 64) & 3)) << 3;   // = ko0 (64 keeps m&3), kept explicit

    for (int k0 = 0; k0 < DIM; k0 += 32) {
        load_lds16(xb + (size_t)(row0 + m0) * DIM + k0 + ko0,      As + tid * 8);
        load_lds16(xb + (size_t)(row0 + 64 + m0) * DIM + k0 + ko1, As + 2048 + tid * 8);
        load_lds16(Bm + (size_t)(col0 + m0) * DIM + k0 + ko0,      Bs + tid * 8);
        load_lds16(Bm + (size_t)(col0 + 64 + m0) * DIM + k0 + ko1, Bs + 2048 + tid * 8);
        __syncthreads();

        short8 a[4], bfr[4];
        #pragma unroll
        for (int i = 0; i < 4; ++i) {
            int r = wm + i * 16 + L;
            a[i] = *(const short8*)(const void*)&As[r * 32 + ((quad ^ (r & 3)) << 3)];
        }
        #pragma unroll
        for (int j = 0; j < 4; ++j) {
            int r = wn + j * 16 + L;
            bfr[j] = *(const short8*)(const void*)&Bs[r * 32 + ((quad ^ (r & 3)) << 3)];
        }

        #pragma unroll
        for (int i = 0; i < 4; ++i)
            #pragma unroll
            for (int j = 0; j < 4; ++j)
                acc[i][j] = __builtin_amdgcn_mfma_f32_16x16x32_bf16(a[i], bfr[j], acc[i][j], 0, 0, 0);
        __syncthreads();
    }

    // transposed epilogue: tb[64][128] bf16 (16KB, reuses As+Bs)
    float biasv[4];
    #pragma unroll
    for (int j = 0; j < 4; ++j) biasv[j] = bias[col0 + wn + j * 16 + L];

    unsigned short* tb = smem;
    #pragma unroll
    for (int round = 0; round < 2; ++round) {
        __syncthreads();
        if ((w >> 1) == round) {          // waves whose wm == round*64
            #pragma unroll
            for (int i = 0; i < 4; ++i)
                #pragma unroll
                for (int j = 0; j < 4; ++j)
                    #pragma unroll
                    for (int r = 0; r < 4; ++r)
                        tb[(i * 16 + quad * 4 + r) * 128 + wn + j * 16 + L] =
                            f2bf(acc[i][j][r] + biasv[j]);
        }
        __syncthreads();
        const int rrow = tid >> 2;
        const int seg = (tid & 3) * 32;
        const uint4* srcv = (const uint4*)&tb[rrow * 128 + seg];
        unsigned short* dst = outp + (size_t)(row0 + round * 64 + rrow) * DIM + col0 + seg;
        #pragma unroll
        for (int ss = 0; ss < 4; ++ss)
            *(uint4*)(dst + ss * 8) = srcv[ss];
    }
}

// ---------------------------------------------------------------------------
// attention: wave-per-row with global work-stealing (1024 blocks x 4 waves =
// 4096 waves over 8192 rows). No block barriers. 4-wide unrolled score and
// v passes. Chunked online softmax (1 chunk normally; 16 chunks of 16 words
// if deg>512) keeps it exact for any degree.
// ---------------------------------------------------------------------------
__global__ __launch_bounds__(256) void attn_kernel(
    const unsigned short* __restrict__ q, const unsigned short* __restrict__ k,
    const unsigned short* __restrict__ v, const unsigned int* __restrict__ mask,
    int* __restrict__ ctr, float* __restrict__ out)
{
    __shared__ unsigned short nbr[4][CAPW];   // 4KB
    __shared__ float pw[4][CAPW];             // 8KB
    __shared__ int cnt[4];

    const int tid = threadIdx.x;
    const int lane = tid & 63;
    const int wid = tid >> 6;
    const float scale = 0.044194173824159220f;   // 1/sqrt(512)

    for (;;) {
        int rowv = 0;
        if (lane == 0) rowv = atomicAdd(ctr, 1);
        const int row = __shfl(rowv, 0, 64);
        if (row >= N_NODES) break;

        const uint4 qv = *(const uint4*)(q + (size_t)row * DIM + lane * 8);
        const unsigned int* __restrict__ mrow = mask + (size_t)row * MASK_WORDS;
        unsigned int mw[4];
        int pc = 0;
        #pragma unroll
        for (int t = 0; t < 4; ++t) {
            mw[t] = mrow[lane + 64 * t];
            pc += __popc(mw[t]);
        }
        const int total = wred_sumi(pc);

        float o[8];
        #pragma unroll
        for (int i = 0; i < 8; ++i) o[i] = 0.f;

        if (total == 0) {
            // all-NEG row -> uniform 1/N over all v rows (prob ~0, exactness)
            for (int j = 0; j < N_NODES; ++j) {
                uint4 vv = *(const uint4*)(v + (size_t)j * DIM + lane * 8);
                o[0] += bf_lo(vv.x); o[1] += bf_hi(vv.x);
                o[2] += bf_lo(vv.y); o[3] += bf_hi(vv.y);
                o[4] += bf_lo(vv.z); o[5] += bf_hi(vv.z);
                o[6] += bf_lo(vv.w); o[7] += bf_hi(vv.w);
            }
            const float sc = 1.0f / N_NODES;
            float4 r0 = {o[0] * sc, o[1] * sc, o[2] * sc, o[3] * sc};
            float4 r1 = {o[4] * sc, o[5] * sc, o[6] * sc, o[7] * sc};
            *(float4*)(out + (size_t)row * DIM + lane * 8) = r0;
            *(float4*)(out + (size_t)row * DIM + lane * 8 + 4) = r1;
            continue;
        }

        const int nchunks = (total <= CAPW) ? 1 : 16;
        float m_run = -3.0e38f, l_run = 0.f;

        for (int c = 0; c < nchunks; ++c) {
            if (lane == 0) cnt[wid] = 0;
            if (nchunks == 1) {
                #pragma unroll
                for (int t = 0; t < 4; ++t) {
                    unsigned int ww = mw[t];
                    while (ww) {
                        int bpos = __ffs(ww) - 1; ww &= ww - 1;
                        int pos = atomicAdd(&cnt[wid], 1);
                        nbr[wid][pos] = (unsigned short)((lane + 64 * t) * 32 + bpos);
                    }
                }
            } else {
                for (int wi = lane; wi < 16; wi += 64) {
                    unsigned int ww = mrow[c * 16 + wi];
                    while (ww) {
                        int bpos = __ffs(ww) - 1; ww &= ww - 1;
                        int pos = atomicAdd(&cnt[wid], 1);
                        nbr[wid][pos] = (unsigned short)((c * 16 + wi) * 32 + bpos);
                    }
                }
            }
            const int cn = cnt[wid];
            if (cn == 0) continue;

            // score pass, 4-wide
            for (int p0 = 0; p0 < cn; p0 += 4) {
                int j0 = nbr[wid][p0];
                int j1 = nbr[wid][(p0 + 1 < cn) ? p0 + 1 : p0];
                int j2 = nbr[wid][(p0 + 2 < cn) ? p0 + 2 : p0];
                int j3 = nbr[wid][(p0 + 3 < cn) ? p0 + 3 : p0];
                uint4 k0v = *(const uint4*)(k + (size_t)j0 * DIM + lane * 8);
                uint4 k1v = *(const uint4*)(k + (size_t)j1 * DIM + lane * 8);
                uint4 k2v = *(const uint4*)(k + (size_t)j2 * DIM + lane * 8);
                uint4 k3v = *(const uint4*)(k + (size_t)j3 * DIM + lane * 8);
                float s0 = wred_sum(dot8(qv, k0v));
                float s1 = wred_sum(dot8(qv, k1v));
                float s2 = wred_sum(dot8(qv, k2v));
                float s3 = wred_sum(dot8(qv, k3v));
                if (lane == 0) {
                    pw[wid][p0] = s0 * scale;
                    if (p0 + 1 < cn) pw[wid][p0 + 1] = s1 * scale;
                    if (p0 + 2 < cn) pw[wid][p0 + 2] = s2 * scale;
                    if (p0 + 3 < cn) pw[wid][p0 + 3] = s3 * scale;
                }
            }

            // chunk softmax (wave-local, online across chunks)
            float mc = -3.0e38f;
            for (int p = lane; p < cn; p += 64) mc = fmaxf(mc, pw[wid][p]);
            mc = wred_max(mc);
            const float mnew = fmaxf(m_run, mc);
            const float f = __expf(m_run - mnew);
            float ls = 0.f;
            for (int p = lane; p < cn; p += 64) {
                float e = __expf(pw[wid][p] - mnew);
                pw[wid][p] = e;
                ls += e;
            }
            l_run = l_run * f + wred_sum(ls);
            m_run = mnew;
            #pragma unroll
            for (int i = 0; i < 8; ++i) o[i] *= f;

            // v pass, 4-wide (clamped lanes get weight 0)
            for (int p0 = 0; p0 < cn; p0 += 4) {
                int j0 = nbr[wid][p0];
                int j1 = nbr[wid][(p0 + 1 < cn) ? p0 + 1 : p0];
                int j2 = nbr[wid][(p0 + 2 < cn) ? p0 + 2 : p0];
                int j3 = nbr[wid][(p0 + 3 < cn) ? p0 + 3 : p0];
                float w0 = pw[wid][p0];
                float w1 = (p0 + 1 < cn) ? pw[wid][p0 + 1] : 0.f;
                float w2 = (p0 + 2 < cn) ? pw[wid][p0 + 2] : 0.f;
                float w3 = (p0 + 3 < cn) ? pw[wid][p0 + 3] : 0.f;
                uint4 v0 = *(const uint4*)(v + (size_t)j0 * DIM + lane * 8);
                uint4 v1 = *(const uint4*)(v + (size_t)j1 * DIM + lane * 8);
                uint4 v2 = *(const uint4*)(v + (size_t)j2 * DIM + lane * 8);
                uint4 v3 = *(const uint4*)(v + (size_t)j3 * DIM + lane * 8);
                o[0] += w0 * bf_lo(v0.x) + w1 * bf_lo(v1.x) + w2 * bf_lo(v2.x) + w3 * bf_lo(v3.x);
                o[1] += w0 * bf_hi(v0.x) + w1 * bf_hi(v1.x) + w2 * bf_hi(v2.x) + w3 * bf_hi(v3.x);
                o[2] += w0 * bf_lo(v0.y) + w1 * bf_lo(v1.y) + w2 * bf_lo(v2.y) + w3 * bf_lo(v3.y);
                o[3] += w0 * bf_hi(v0.y) + w1 * bf_hi(v1.y) + w2 * bf_hi(v2.y) + w3 * bf_hi(v3.y);
                o[4] += w0 * bf_lo(v0.z) + w1 * bf_lo(v1.z) + w2 * bf_lo(v2.z) + w3 * bf_lo(v3.z);
                o[5] += w0 * bf_hi(v0.z) + w1 * bf_hi(v1.z) + w2 * bf_hi(v2.z) + w3 * bf_hi(v3.z);
                o[6] += w0 * bf_lo(v0.w) + w1 * bf_lo(v1.w) + w2 * bf_lo(v2.w) + w3 * bf_lo(v3.w);
                o[7] += w0 * bf_hi(v0.w) + w1 * bf_hi(v1.w) + w2 * bf_hi(v2.w) + w3 * bf_hi(v3.w);
            }
        }

        const float inv = 1.0f / l_run;
        float4 r0 = {o[0] * inv, o[1] * inv, o[2] * inv, o[3] * inv};
        float4 r1 = {o[4] * inv, o[5] * inv, o[6] * inv, o[7] * inv};
        *(float4*)(out + (size_t)row * DIM + lane * 8) = r0;
        *(float4*)(out + (size_t)row * DIM + lane * 8 + 4) = r1;
    }
}

// ---------------------------------------------------------------------------
extern "C" void kernel_launch(void* const* d_in, const int* in_sizes, int n_in,
                              void* d_out, int out_size, void* d_ws, size_t ws_size,
                              hipStream_t stream)
{
    const float* x  = (const float*)d_in[0];
    const int*   ei = (const int*)d_in[1];
    const float* Wq = (const float*)d_in[2];
    const float* bq = (const float*)d_in[3];
    const float* Wk = (const float*)d_in[4];
    const float* bk = (const float*)d_in[5];
    const float* Wv = (const float*)d_in[6];
    const float* bv = (const float*)d_in[7];
    float* out = (float*)d_out;

    const int E = in_sizes[1] / 2;
    const size_t NM = (size_t)N_NODES * DIM;

    unsigned short* xb = (unsigned short*)d_ws;
    unsigned short* Wt = xb + NM;
    unsigned short* qkv = Wt + (size_t)3 * DIM * DIM;   // q | k | v contiguous
    unsigned short* qb = qkv;
    unsigned short* kb = qkv + NM;
    unsigned short* vb = qkv + 2 * NM;
    unsigned int* mask = (unsigned int*)(qkv + 3 * NM);
    int* ctr = (int*)(mask + (size_t)N_NODES * MASK_WORDS);

    prep1<<<4864, 256, 0, stream>>>(x, xb, Wq, Wk, Wv, Wt, mask, ctr);
    prep2<<<(E + 255) / 256, 256, 0, stream>>>(ei, mask, E);

    mfma_gemm<<<768, 256, 0, stream>>>(xb, Wt, bq, bk, bv, qkv);

    attn_kernel<<<1024, 256, 0, stream>>>(qb, kb, vb, mask, ctr, out);
}

// Round 6
// 187.050 us; speedup vs baseline: 1.5347x; 1.5347x over previous
//
#include <hip/hip_runtime.h>

// N=8192 nodes, D=512, E=262144. NEG=-1e6 => exp underflows to exactly 0,
// so softmax is EXACTLY sparse over each row's neighbor set (bitmask dedupes
// duplicate edges, matching .at[].set(1.0) idempotence).
//
// R6: gemm = wave-private LDS staging, NO K-loop barriers (wave-local
//     s_waitcnt replaces __syncthreads convoy). attn = wave-per-row (static,
//     8192 waves) + fused single-pass no-max softmax (safe: |s*scale| <~ 30
//     by Cauchy-Schwarz on normalized inputs) + prefix-scan sorted compaction.

#define N_NODES 8192
#define DIM 512
#define MASK_WORDS 256   // 8192 bits / 32
#define CAPW 512         // per-wave neighbor chunk capacity

typedef __attribute__((ext_vector_type(8))) short short8;
typedef __attribute__((ext_vector_type(4))) float f32x4;

__device__ __forceinline__ unsigned short f2bf(float f) {
    unsigned int u = __float_as_uint(f);
    u += 0x7fffu + ((u >> 16) & 1u);          // round-to-nearest-even
    return (unsigned short)(u >> 16);
}
__device__ __forceinline__ float bf_lo(unsigned int w) { return __uint_as_float(w << 16); }
__device__ __forceinline__ float bf_hi(unsigned int w) { return __uint_as_float(w & 0xffff0000u); }

__device__ __forceinline__ float wred_sum(float s) {
    #pragma unroll
    for (int off = 1; off <= 32; off <<= 1) s += __shfl_xor(s, off, 64);
    return s;
}
__device__ __forceinline__ int wred_sumi(int s) {
    #pragma unroll
    for (int off = 1; off <= 32; off <<= 1) s += __shfl_xor(s, off, 64);
    return s;
}
__device__ __forceinline__ float dot8(uint4 a, uint4 b) {
    return bf_lo(a.x) * bf_lo(b.x) + bf_hi(a.x) * bf_hi(b.x)
         + bf_lo(a.y) * bf_lo(b.y) + bf_hi(a.y) * bf_hi(b.y)
         + bf_lo(a.z) * bf_lo(b.z) + bf_hi(a.z) * bf_hi(b.z)
         + bf_lo(a.w) * bf_lo(b.w) + bf_hi(a.w) * bf_hi(b.w);
}

// ---------------------------------------------------------------------------
// prep1: [0,4096) convert x -> bf16 AND zero 2KB of mask each |
//        [4096,4864) transpose-convert W -> Wt
// ---------------------------------------------------------------------------
__global__ __launch_bounds__(256) void prep1(
    const float* __restrict__ x, unsigned short* __restrict__ xb,
    const float* __restrict__ Wq, const float* __restrict__ Wk,
    const float* __restrict__ Wv, unsigned short* __restrict__ Wt,
    unsigned int* __restrict__ mask)
{
    __shared__ float sm[32][33];
    const int b = blockIdx.x;
    if (b < 4096) {
        int i = b * 256 + threadIdx.x;
        float4 f = ((const float4*)x)[i];
        ushort4 o;
        o.x = f2bf(f.x); o.y = f2bf(f.y); o.z = f2bf(f.z); o.w = f2bf(f.w);
        ((ushort4*)xb)[i] = o;
        ((uint2*)mask)[i] = make_uint2(0u, 0u);     // 4096*256*8B = 8MB
    } else {
        int bb = b - 4096;
        int which = bb >> 8, t = bb & 255;
        const float* __restrict__ W = (which == 0) ? Wq : (which == 1) ? Wk : Wv;
        unsigned short* __restrict__ outp = Wt + (size_t)which * DIM * DIM;
        int n0 = (t & 15) * 32, k0 = (t >> 4) * 32;
        int tx = threadIdx.x & 31, ty = threadIdx.x >> 5;
        #pragma unroll
        for (int r = 0; r < 4; ++r)
            sm[ty + 8 * r][tx] = W[(size_t)(k0 + ty + 8 * r) * DIM + n0 + tx];
        __syncthreads();
        #pragma unroll
        for (int r = 0; r < 4; ++r)
            outp[(size_t)(n0 + ty + 8 * r) * DIM + k0 + tx] = f2bf(sm[tx][ty + 8 * r]);
    }
}

// prep2: edge scatter (needs fully-zeroed mask)
__global__ __launch_bounds__(256) void prep2(
    const int* __restrict__ ei, unsigned int* __restrict__ mask, int E)
{
    int e = blockIdx.x * 256 + threadIdx.x;
    if (e >= E) return;
    int src = ei[e];
    int dst = ei[E + e];
    atomicOr(&mask[(size_t)src * MASK_WORDS + (dst >> 5)], 1u << (dst & 31));
}

// ---------------------------------------------------------------------------
// bf16 MFMA GEMM, 128x128 tile, BK=32. Wave-PRIVATE staging: each wave owns
// an 8KB LDS region (64x32 A + 64x32 B for its wm/wn) filled by
// global_load_lds; ordering via wave-local s_waitcnt(0) — NO __syncthreads
// in the K-loop, so no barrier convoy. XOR-swizzled k-group placement keeps
// frag ds_read_b128 conflicts at 4-way. Vectorized transposed epilogue.
// ---------------------------------------------------------------------------
__device__ __forceinline__ void load_lds16(const unsigned short* g, unsigned short* l) {
    __builtin_amdgcn_global_load_lds(
        (const __attribute__((address_space(1))) unsigned int*)g,
        (__attribute__((address_space(3))) unsigned int*)l, 16, 0, 0);
}

__global__ __launch_bounds__(256) void mfma_gemm(
    const unsigned short* __restrict__ xb, const unsigned short* __restrict__ Wt,
    const float* __restrict__ bq, const float* __restrict__ bk, const float* __restrict__ bv,
    unsigned short* __restrict__ qkv)
{
    const int p = blockIdx.x;
    const int xcd = p & 7;
    const int s = p >> 3;             // 0..95
    const int mloc = s / 12;          // 0..7
    const int n = s - 12 * mloc;      // 0..11
    const int which = n >> 2;
    const int row0 = (xcd * 8 + mloc) << 7;
    const int col0 = (n & 3) << 7;

    const unsigned short* __restrict__ Bm = Wt + (size_t)which * DIM * DIM;
    const float* __restrict__ bias = (which == 0) ? bq : (which == 1) ? bk : bv;
    unsigned short* __restrict__ outp = qkv + (size_t)which * N_NODES * DIM;

    const int tid = threadIdx.x;
    const int lane = tid & 63;
    const int w = tid >> 6;
    const int wm = (w >> 1) * 64;
    const int wn = (w & 1) * 64;
    const int L = lane & 15;
    const int quad = lane >> 4;

    __shared__ unsigned short smem[16384];        // 32KB: 4 waves x (2048 A + 2048 B)
    unsigned short* Aw = smem + w * 4096;
    unsigned short* Bw = Aw + 2048;

    f32x4 zero = {0.f, 0.f, 0.f, 0.f};
    f32x4 acc[4][4];
    #pragma unroll
    for (int i = 0; i < 4; ++i)
        #pragma unroll
        for (int j = 0; j < 4; ++j) acc[i][j] = zero;

    // per-inst t (t=0..3): chunk = t*64+lane, m = chunk>>2, cg = chunk&3,
    // global ko = (cg ^ (m&3))*8 (XOR swizzle). HW adds lane*16B to lds dst.
    int gm[4], gko[4];
    #pragma unroll
    for (int t = 0; t < 4; ++t) {
        int chunk = t * 64 + lane;
        gm[t] = chunk >> 2;
        gko[t] = ((chunk & 3) ^ (gm[t] & 3)) << 3;
    }
    const unsigned short* arow = xb + (size_t)(row0 + wm) * DIM;
    const unsigned short* brow = Bm + (size_t)(col0 + wn) * DIM;

    for (int k0 = 0; k0 < DIM; k0 += 32) {
        __builtin_amdgcn_s_waitcnt(0);            // prior ds_reads done (WAR)
        #pragma unroll
        for (int t = 0; t < 4; ++t)
            load_lds16(arow + (size_t)gm[t] * DIM + k0 + gko[t], Aw + t * 512);
        #pragma unroll
        for (int t = 0; t < 4; ++t)
            load_lds16(brow + (size_t)gm[t] * DIM + k0 + gko[t], Bw + t * 512);
        __builtin_amdgcn_s_waitcnt(0);            // staging visible in LDS
        __builtin_amdgcn_sched_barrier(0);

        short8 a[4], bfr[4];
        #pragma unroll
        for (int i = 0; i < 4; ++i) {
            int r = i * 16 + L;
            a[i] = *(const short8*)(const void*)&Aw[r * 32 + ((quad ^ (r & 3)) << 3)];
        }
        #pragma unroll
        for (int j = 0; j < 4; ++j) {
            int r = j * 16 + L;
            bfr[j] = *(const short8*)(const void*)&Bw[r * 32 + ((quad ^ (r & 3)) << 3)];
        }

        #pragma unroll
        for (int i = 0; i < 4; ++i)
            #pragma unroll
            for (int j = 0; j < 4; ++j)
                acc[i][j] = __builtin_amdgcn_mfma_f32_16x16x32_bf16(a[i], bfr[j], acc[i][j], 0, 0, 0);
        __builtin_amdgcn_sched_barrier(0);
    }

    // transposed epilogue: tb[64][128] bf16 (16KB, reuses smem)
    float biasv[4];
    #pragma unroll
    for (int j = 0; j < 4; ++j) biasv[j] = bias[col0 + wn + j * 16 + L];

    unsigned short* tb = smem;
    #pragma unroll
    for (int round = 0; round < 2; ++round) {
        __syncthreads();
        if ((w >> 1) == round) {          // waves whose wm == round*64
            #pragma unroll
            for (int i = 0; i < 4; ++i)
                #pragma unroll
                for (int j = 0; j < 4; ++j)
                    #pragma unroll
                    for (int r = 0; r < 4; ++r)
                        tb[(i * 16 + quad * 4 + r) * 128 + wn + j * 16 + L] =
                            f2bf(acc[i][j][r] + biasv[j]);
        }
        __syncthreads();
        const int rrow = tid >> 2;
        const int seg = (tid & 3) * 32;
        const uint4* srcv = (const uint4*)&tb[rrow * 128 + seg];
        unsigned short* dst = outp + (size_t)(row0 + round * 64 + rrow) * DIM + col0 + seg;
        #pragma unroll
        for (int ss = 0; ss < 4; ++ss)
            *(uint4*)(dst + ss * 8) = srcv[ss];
    }
}

// ---------------------------------------------------------------------------
// attention: static wave-per-row (2048 blocks x 4 waves = 8192 waves).
// Fused single pass: w = exp(s*scale) (no max — bounded), o += w*v, l += w.
// l_run is wave-uniform (post-butterfly s is identical on all lanes).
// Sorted neighbor compaction via prefix scan (no atomics, ascending j).
// ---------------------------------------------------------------------------
__device__ __forceinline__ void fused_pass(
    const unsigned short* __restrict__ k, const unsigned short* __restrict__ v,
    const unsigned short* nbrw, int cn, uint4 qv, int lane,
    float* o, float& l_run)
{
    const float scale = 0.044194173824159220f;   // 1/sqrt(512)
    for (int p0 = 0; p0 < cn; p0 += 4) {
        int j0 = nbrw[p0];
        int j1 = nbrw[(p0 + 1 < cn) ? p0 + 1 : p0];
        int j2 = nbrw[(p0 + 2 < cn) ? p0 + 2 : p0];
        int j3 = nbrw[(p0 + 3 < cn) ? p0 + 3 : p0];
        uint4 k0v = *(const uint4*)(k + (size_t)j0 * DIM + lane * 8);
        uint4 k1v = *(const uint4*)(k + (size_t)j1 * DIM + lane * 8);
        uint4 k2v = *(const uint4*)(k + (size_t)j2 * DIM + lane * 8);
        uint4 k3v = *(const uint4*)(k + (size_t)j3 * DIM + lane * 8);
        uint4 v0 = *(const uint4*)(v + (size_t)j0 * DIM + lane * 8);
        uint4 v1 = *(const uint4*)(v + (size_t)j1 * DIM + lane * 8);
        uint4 v2 = *(const uint4*)(v + (size_t)j2 * DIM + lane * 8);
        uint4 v3 = *(const uint4*)(v + (size_t)j3 * DIM + lane * 8);
        float s0 = wred_sum(dot8(qv, k0v));
        float s1 = wred_sum(dot8(qv, k1v));
        float s2 = wred_sum(dot8(qv, k2v));
        float s3 = wred_sum(dot8(qv, k3v));
        float w0 = __expf(s0 * scale);
        float w1 = (p0 + 1 < cn) ? __expf(s1 * scale) : 0.f;
        float w2 = (p0 + 2 < cn) ? __expf(s2 * scale) : 0.f;
        float w3 = (p0 + 3 < cn) ? __expf(s3 * scale) : 0.f;
        l_run += w0 + w1 + w2 + w3;
        o[0] += w0 * bf_lo(v0.x) + w1 * bf_lo(v1.x) + w2 * bf_lo(v2.x) + w3 * bf_lo(v3.x);
        o[1] += w0 * bf_hi(v0.x) + w1 * bf_hi(v1.x) + w2 * bf_hi(v2.x) + w3 * bf_hi(v3.x);
        o[2] += w0 * bf_lo(v0.y) + w1 * bf_lo(v1.y) + w2 * bf_lo(v2.y) + w3 * bf_lo(v3.y);
        o[3] += w0 * bf_hi(v0.y) + w1 * bf_hi(v1.y) + w2 * bf_hi(v2.y) + w3 * bf_hi(v3.y);
        o[4] += w0 * bf_lo(v0.z) + w1 * bf_lo(v1.z) + w2 * bf_lo(v2.z) + w3 * bf_lo(v3.z);
        o[5] += w0 * bf_hi(v0.z) + w1 * bf_hi(v1.z) + w2 * bf_hi(v2.z) + w3 * bf_hi(v3.z);
        o[6] += w0 * bf_lo(v0.w) + w1 * bf_lo(v1.w) + w2 * bf_lo(v2.w) + w3 * bf_lo(v3.w);
        o[7] += w0 * bf_hi(v0.w) + w1 * bf_hi(v1.w) + w2 * bf_hi(v2.w) + w3 * bf_hi(v3.w);
    }
}

__device__ __forceinline__ int wave_excl_scan(int pc, int lane) {
    int incl = pc;
    #pragma unroll
    for (int off = 1; off <= 32; off <<= 1) {
        int nv = __shfl_up(incl, off, 64);
        if (lane >= off) incl += nv;
    }
    return incl;   // inclusive; excl = incl - pc
}

__global__ __launch_bounds__(256) void attn_kernel(
    const unsigned short* __restrict__ q, const unsigned short* __restrict__ k,
    const unsigned short* __restrict__ v, const unsigned int* __restrict__ mask,
    float* __restrict__ out)
{
    __shared__ unsigned short nbr[4][CAPW];   // 4KB total

    const int tid = threadIdx.x;
    const int lane = tid & 63;
    const int wid = tid >> 6;
    const int row = blockIdx.x * 4 + wid;

    const uint4 qv = *(const uint4*)(q + (size_t)row * DIM + lane * 8);
    const unsigned int* __restrict__ mrow = mask + (size_t)row * MASK_WORDS;

    // lane holds words [lane*4, lane*4+4) -> ascending order after scan
    const uint4 mv = ((const uint4*)mrow)[lane];
    unsigned int wds[4] = {mv.x, mv.y, mv.z, mv.w};
    int pc = __popc(wds[0]) + __popc(wds[1]) + __popc(wds[2]) + __popc(wds[3]);
    const int total = wred_sumi(pc);

    float o[8];
    #pragma unroll
    for (int i = 0; i < 8; ++i) o[i] = 0.f;

    if (total == 0) {
        // all-NEG row -> uniform 1/N over all v rows (prob ~0, exactness only)
        for (int j = 0; j < N_NODES; ++j) {
            uint4 vv = *(const uint4*)(v + (size_t)j * DIM + lane * 8);
            o[0] += bf_lo(vv.x); o[1] += bf_hi(vv.x);
            o[2] += bf_lo(vv.y); o[3] += bf_hi(vv.y);
            o[4] += bf_lo(vv.z); o[5] += bf_hi(vv.z);
            o[6] += bf_lo(vv.w); o[7] += bf_hi(vv.w);
        }
        const float sc = 1.0f / N_NODES;
        float4 r0 = {o[0] * sc, o[1] * sc, o[2] * sc, o[3] * sc};
        float4 r1 = {o[4] * sc, o[5] * sc, o[6] * sc, o[7] * sc};
        *(float4*)(out + (size_t)row * DIM + lane * 8) = r0;
        *(float4*)(out + (size_t)row * DIM + lane * 8 + 4) = r1;
        return;
    }

    float l_run = 0.f;

    if (total <= CAPW) {
        // single chunk: prefix-scan compaction, ascending neighbor ids
        int pos = wave_excl_scan(pc, lane) - pc;
        #pragma unroll
        for (int t = 0; t < 4; ++t) {
            unsigned int ww = wds[t];
            int base = (lane * 4 + t) * 32;
            while (ww) {
                int b = __ffs(ww) - 1; ww &= ww - 1;
                nbr[wid][pos++] = (unsigned short)(base + b);
            }
        }
        fused_pass(k, v, nbr[wid], total, qv, lane, o, l_run);
    } else {
        // 16 chunks of 16 words (<=512 bits each) — exact for any degree
        for (int c = 0; c < 16; ++c) {
            unsigned int ww = 0;
            if (lane < 16) ww = mrow[c * 16 + lane];
            int pcc = __popc(ww);
            int incl = wave_excl_scan(pcc, lane);
            int cn = __shfl(incl, 63, 64);
            if (cn == 0) continue;
            int pos = incl - pcc;
            int base = (c * 16 + lane) * 32;
            while (ww) {
                int b = __ffs(ww) - 1; ww &= ww - 1;
                nbr[wid][pos++] = (unsigned short)(base + b);
            }
            fused_pass(k, v, nbr[wid], cn, qv, lane, o, l_run);
        }
    }

    const float inv = 1.0f / l_run;
    float4 r0 = {o[0] * inv, o[1] * inv, o[2] * inv, o[3] * inv};
    float4 r1 = {o[4] * inv, o[5] * inv, o[6] * inv, o[7] * inv};
    *(float4*)(out + (size_t)row * DIM + lane * 8) = r0;
    *(float4*)(out + (size_t)row * DIM + lane * 8 + 4) = r1;
}

// ---------------------------------------------------------------------------
extern "C" void kernel_launch(void* const* d_in, const int* in_sizes, int n_in,
                              void* d_out, int out_size, void* d_ws, size_t ws_size,
                              hipStream_t stream)
{
    const float* x  = (const float*)d_in[0];
    const int*   ei = (const int*)d_in[1];
    const float* Wq = (const float*)d_in[2];
    const float* bq = (const float*)d_in[3];
    const float* Wk = (const float*)d_in[4];
    const float* bk = (const float*)d_in[5];
    const float* Wv = (const float*)d_in[6];
    const float* bv = (const float*)d_in[7];
    float* out = (float*)d_out;

    const int E = in_sizes[1] / 2;
    const size_t NM = (size_t)N_NODES * DIM;

    unsigned short* xb = (unsigned short*)d_ws;
    unsigned short* Wt = xb + NM;
    unsigned short* qkv = Wt + (size_t)3 * DIM * DIM;   // q | k | v contiguous
    unsigned short* qb = qkv;
    unsigned short* kb = qkv + NM;
    unsigned short* vb = qkv + 2 * NM;
    unsigned int* mask = (unsigned int*)(qkv + 3 * NM);

    prep1<<<4864, 256, 0, stream>>>(x, xb, Wq, Wk, Wv, Wt, mask);
    prep2<<<(E + 255) / 256, 256, 0, stream>>>(ei, mask, E);

    mfma_gemm<<<768, 256, 0, stream>>>(xb, Wt, bq, bk, bv, qkv);

    attn_kernel<<<N_NODES / 4, 256, 0, stream>>>(qb, kb, vb, mask, out);
}